// Round 3
// baseline (249.524 us; speedup 1.0000x reference)
//
#include <hip/hip_runtime.h>
#include <hip/hip_bf16.h>

// MonarchOutProjection: out[t][r*32+q] = sum_p R[q][r][p] * sum_m L[p][q][m] * x[t][m*32+p]
// Round 5: kill the transpose cost. r2 and r4 both hit 87us with different phase
// structures -> the invariant is instruction count: ~190 LDS ops (mostly scalar,
// 4-way) + ~1000 VALU per thread. Fix: swap stage-1 operand order (A = x, B = L).
//  - stage-1 A-frag wants lane(t, m-chunk) to hold 8 CONSECUTIVE channels
//    x[t][m*32 + p..p+7] -> divergent global_load_dwordx4 pairs straight from
//    L3-resident x; in-register cvt_pk transpose. No LDS, no stage-in, no b1 reads.
//  - stage-1 output = 4 consecutive TOKENS per lane -> y1[q][p][t] (strides
//    t:1, p:18, q:584) via paired b32 writes (4-way); stage-2 b2 reads from this
//    layout are 2-way conflict-FREE (bank = 8*quad + 9j + tl/2).
//  - stage-2 unchanged shape (Rb frag as A); y2 -> [t][ch] (stride 1028) scalar
//    writes (4-way), dump b64 reads (structural 4) + coalesced float4 stores.
//  - 3 barriers total, lgkm-only (no vmcnt drain; Rb loads fly across barrier 1).
//  - prep_weights UNCHANGED: the frag layout is valid in either operand slot.

typedef __attribute__((ext_vector_type(8))) short short8;
typedef __attribute__((ext_vector_type(4))) float floatx4;

#define PS 18        // y1 p-stride (elems): odd*2 -> reader quad stays bank-alive
#define QS 584       // y1 q-stride = 32*18 + 8
#define TS 1028      // y2 t-stride (elems): 2056 B, 8B-aligned for b64 dump reads

__device__ __forceinline__ unsigned int pack2bf(float a, float b) {
    __hip_bfloat162 h = __float22bfloat162_rn(float2{a, b});  // packed cvt
    return *(unsigned int*)&h;
}
__device__ __forceinline__ float bf2f(unsigned int u16) {
    return __uint_as_float(u16 << 16);
}

// Barrier with LDS-only drain: never drain vmcnt (keeps global loads in flight).
__device__ __forceinline__ void block_sync() {
    asm volatile("s_waitcnt lgkmcnt(0)" ::: "memory");
    __builtin_amdgcn_s_barrier();
    asm volatile("" ::: "memory");
}

// Lb[(p*2+qt)*64 + lane] (short8) = L[p][q=qt*16+(lane&15)][m=(lane>>4)*8 .. +8] as bf16.
// Same for Rb. Valid as A-frag (row=lane&15, k=(lane>>4)*8+j) or as B-frag
// (k=(lane>>4)*8+j, col=lane&15) -- the two slots mirror. 8192 threads, one short8 each.
__global__ void prep_weights(const float* __restrict__ L, const float* __restrict__ R,
                             unsigned short* __restrict__ Lb, unsigned short* __restrict__ Rb) {
    const int t = blockIdx.x * 256 + threadIdx.x;          // 0..8191
    const float* src        = (t < 4096) ? L : R;
    unsigned short* dst     = (t < 4096) ? Lb : Rb;
    const int i    = t & 4095;                             // (p*2+qt)*64 + lane
    const int lane = i & 63;
    const int pq   = i >> 6;
    const int p    = pq >> 1;
    const int qt   = pq & 1;
    const int q    = qt * 16 + (lane & 15);
    const int m0   = (lane >> 4) * 8;
    const float* s = src + (p * 32 + q) * 32 + m0;
    uint4 o;
    o.x = pack2bf(s[0], s[1]);
    o.y = pack2bf(s[2], s[3]);
    o.z = pack2bf(s[4], s[5]);
    o.w = pack2bf(s[6], s[7]);
    *(uint4*)(dst + (size_t)i * 8) = o;
}

__global__ __launch_bounds__(256, 3)
void monarch_kernel(const float* __restrict__ x,
                    const unsigned short* __restrict__ Lb,
                    const unsigned short* __restrict__ Rb,
                    float* __restrict__ out) {
    // One allocation, two lives: y1[q][p][t] (18688 elems) then y2[t][ch] (16448).
    __shared__ __align__(16) unsigned short lds[18688];    // 37376 B -> 4 blocks/CU by LDS

    const int tid  = threadIdx.x;
    const int w    = tid >> 6;
    const int lane = tid & 63;
    const int tl   = lane & 15;       // MFMA row/col index within 16
    const int quad = lane >> 4;
    const long tok0 = (long)blockIdx.x * 16;

    // ---------- stage 1 inputs: divergent 8x8 global gather ----------
    // Lane (tl,quad) loads x[tok0+tl][(quad*8+j)*32 + w*8 .. +8] for j=0..7:
    // 16 dwordx4, 32B/lane granularity, L3-resident -> HW coalescer does the transpose.
    const float* xb = x + (tok0 + tl) * 1024 + w * 8;
    float4 xa[8], xc[8];
    #pragma unroll
    for (int j = 0; j < 8; ++j) {
        xa[j] = *(const float4*)(xb + (quad * 8 + j) * 32);
        xc[j] = *(const float4*)(xb + (quad * 8 + j) * 32 + 4);
    }

    // A-frags: a1[pp][j] = bf16(x[tl][(quad*8+j)*32 + w*8+pp])  (in-register transpose)
    short8 a1[8];
    #pragma unroll
    for (int pp = 0; pp < 8; ++pp) {
        #pragma unroll
        for (int r = 0; r < 4; ++r) {
            const float lo = (pp < 4) ? xa[2 * r    ][pp] : xc[2 * r    ][pp - 4];
            const float hi = (pp < 4) ? xa[2 * r + 1][pp] : xc[2 * r + 1][pp - 4];
            ((unsigned int*)&a1[pp])[r] = pack2bf(lo, hi);
        }
    }

    // L frags (B-operand): issued after x consumed -> xa/xc regs recycled.
    short8 lb[8][2];
    #pragma unroll
    for (int pp = 0; pp < 8; ++pp) {
        const int p = w * 8 + pp;
        lb[pp][0] = *(const short8*)(Lb + (size_t)((p * 2 + 0) * 64 + lane) * 8);
        lb[pp][1] = *(const short8*)(Lb + (size_t)((p * 2 + 1) * 64 + lane) * 8);
    }

    // ---------- stage 1: D = X^T * L^T -> lane holds y1[q=qt*16+tl][t=quad*4+0..3] ----------
    #pragma unroll
    for (int pp = 0; pp < 8; ++pp) {
        const int p = w * 8 + pp;
        #pragma unroll
        for (int qt = 0; qt < 2; ++qt) {
            floatx4 acc = {0.f, 0.f, 0.f, 0.f};
            acc = __builtin_amdgcn_mfma_f32_16x16x32_bf16(a1[pp], lb[pp][qt], acc, 0, 0, 0);
            // y1[q][p][t]: 4 consecutive t -> paired b32 writes (ds_write2-able)
            const int el = (qt * 16 + tl) * QS + p * PS + quad * 4;
            *(unsigned int*)&lds[el]     = pack2bf(acc[0], acc[1]);
            *(unsigned int*)&lds[el + 2] = pack2bf(acc[2], acc[3]);
        }
    }

    // R frags (A-operand): issue BEFORE barrier so the L2 latency hides under it.
    short8 ra[8][2];
    #pragma unroll
    for (int qq = 0; qq < 8; ++qq) {
        const int q = w * 8 + qq;
        ra[qq][0] = *(const short8*)(Rb + (size_t)((q * 2 + 0) * 64 + lane) * 8);
        ra[qq][1] = *(const short8*)(Rb + (size_t)((q * 2 + 1) * 64 + lane) * 8);
    }
    block_sync();   // 1: y1 visible to all waves

    // ---------- stage 2: b2 reads (2-way free) + MFMA; pack y2 in regs ----------
    unsigned long long y2p[8][2];
    #pragma unroll
    for (int qq = 0; qq < 8; ++qq) {
        const int q = w * 8 + qq;
        short8 b2;
        #pragma unroll
        for (int j = 0; j < 8; ++j)       // B2[k=p=quad*8+j][col=t=tl]
            b2[j] = (short)lds[q * QS + (quad * 8 + j) * PS + tl];
        #pragma unroll
        for (int rt = 0; rt < 2; ++rt) {
            floatx4 z = {0.f, 0.f, 0.f, 0.f};
            const floatx4 acc =
                __builtin_amdgcn_mfma_f32_16x16x32_bf16(ra[qq][rt], b2, z, 0, 0, 0);
            y2p[qq][rt] = ((unsigned long long)pack2bf(acc[2], acc[3]) << 32)
                        | pack2bf(acc[0], acc[1]);
        }
    }
    block_sync();   // 2: all y1 reads done -> buffer reusable as y2

    // ---------- y2 -> lds[t][ch], ch = r*32+q (lane holds 4 consecutive r) ----------
    #pragma unroll
    for (int qq = 0; qq < 8; ++qq) {
        const int q = w * 8 + qq;
        #pragma unroll
        for (int rt = 0; rt < 2; ++rt) {
            const unsigned long long v = y2p[qq][rt];
            #pragma unroll
            for (int rr = 0; rr < 4; ++rr) {
                const int r = rt * 16 + quad * 4 + rr;
                lds[tl * TS + r * 32 + q] = (unsigned short)(v >> (16 * rr));
            }
        }
    }
    block_sync();   // 3: y2 visible

    // ---------- dump: b64 LDS reads + coalesced float4 stores ----------
    const int c = tid * 4;
    #pragma unroll
    for (int t = 0; t < 16; ++t) {
        const unsigned long long v = *(const unsigned long long*)&lds[t * TS + c];
        const unsigned int lo = (unsigned int)v;
        const unsigned int hi = (unsigned int)(v >> 32);
        float4 o;
        o.x = bf2f(lo & 0xffffu); o.y = bf2f(lo >> 16);
        o.z = bf2f(hi & 0xffffu); o.w = bf2f(hi >> 16);
        *(float4*)(out + (tok0 + t) * 1024 + c) = o;
    }
}

extern "C" void kernel_launch(void* const* d_in, const int* in_sizes, int n_in,
                              void* d_out, int out_size, void* d_ws, size_t ws_size,
                              hipStream_t stream) {
    const float* x = (const float*)d_in[0];   // (8, 4096, 1024) fp32
    const float* L = (const float*)d_in[1];   // (32, 32, 32) fp32
    const float* R = (const float*)d_in[2];   // (32, 32, 32) fp32
    float* out = (float*)d_out;

    unsigned short* Lb = (unsigned short*)d_ws;          // 32768 bf16 = 64 KiB
    unsigned short* Rb = Lb + 32768;                     // 32768 bf16 = 64 KiB

    prep_weights<<<32, 256, 0, stream>>>(L, R, Lb, Rb);  // L2-resident after

    const int n_tokens = 8 * 4096;
    const int grid = n_tokens / 16;                      // 2048 blocks x 16 tokens
    monarch_kernel<<<grid, 256, 0, stream>>>(x, Lb, Rb, out);
}